// Round 13
// baseline (398.696 us; speedup 1.0000x reference)
//
#include <hip/hip_runtime.h>
#include <hip/hip_bf16.h>

#define N_NODES   50000
#define N_EDGES   800000
#define NUM_GRAPHS 256
#define IN_DIM    128
#define HD        64
#define EPS       1e-5f
#define SCAN_NB   196      // ceil(50000/256)
#define NB_HEAD   64       // head kernel grid (must be <= CU count for co-residency)
#define GATHER_NB 12500    // blocks per half-pass (4 nodes/block)

typedef __hip_bfloat16 bf16;

// ---------------- diagnostics ----------------
__global__ void k_diag(float* __restrict__ out, int n, float v) {
    int t = blockIdx.x * 256 + threadIdx.x;
    if (t < n) out[t] = v;
}

// ---------------- CSR build (+ graph bounds for pooling) ----------------
__global__ void k_count(const int* __restrict__ dst, const int* __restrict__ batch,
                        int* __restrict__ cnti, int* __restrict__ pos,
                        int* __restrict__ gb) {
    int e = blockIdx.x * 256 + threadIdx.x;
    if (e < N_EDGES) pos[e] = atomicAdd(&cnti[dst[e]], 1);
    // graph bounds: gb[g] = first node index with batch >= g (batch is sorted)
    if (e < N_NODES) {
        int bg = batch[e];
        int bnext = (e + 1 < N_NODES) ? batch[e + 1] : NUM_GRAPHS;
        if (e == 0) {
            for (int g = 0; g <= bg; ++g) gb[g] = 0;
        }
        for (int g = bg + 1; g <= bnext; ++g) gb[g] = e + 1;
    }
}

__global__ void k_scan1(const int* __restrict__ cnti, int* __restrict__ off,
                        int* __restrict__ bsum) {
    __shared__ int wsum[4];
    int idx = blockIdx.x * 256 + threadIdx.x;
    int lane = threadIdx.x & 63, wid = threadIdx.x >> 6;
    int v = (idx < N_NODES) ? cnti[idx] : 0;
    int s = v;
    #pragma unroll
    for (int o = 1; o < 64; o <<= 1) {
        int u = __shfl_up(s, o);
        if (lane >= o) s += u;
    }
    if (lane == 63) wsum[wid] = s;
    __syncthreads();
    int wbase = 0;
    #pragma unroll
    for (int w = 0; w < 4; w++) wbase += (w < wid) ? wsum[w] : 0;
    if (idx < N_NODES) off[idx] = wbase + s - v;
    if (threadIdx.x == 255) bsum[blockIdx.x] = wbase + s;
}

__global__ void k_scan3(int* __restrict__ off, const int* __restrict__ bsum,
                        const int* __restrict__ gb, float* __restrict__ invc) {
    __shared__ int wsum[4];
    __shared__ int spre;
    int lane = threadIdx.x & 63, wid = threadIdx.x >> 6;
    int v = (threadIdx.x < blockIdx.x) ? bsum[threadIdx.x] : 0;
    #pragma unroll
    for (int o = 32; o > 0; o >>= 1) v += __shfl_down(v, o);
    if (lane == 0) wsum[wid] = v;
    __syncthreads();
    if (threadIdx.x == 0) spre = wsum[0] + wsum[1] + wsum[2] + wsum[3];
    __syncthreads();
    int pre = spre;
    int idx = blockIdx.x * 256 + threadIdx.x;
    if (idx < N_NODES) off[idx] += pre;
    else if (idx == N_NODES) off[N_NODES] = N_EDGES;
    // per-graph 1/count for fused pooling (gb ready since k_count)
    if (blockIdx.x == 0 && threadIdx.x < NUM_GRAPHS) {
        int c0 = gb[threadIdx.x], c1 = gb[threadIdx.x + 1];
        invc[threadIdx.x] = 1.0f / (float)max(c1 - c0, 1);
    }
}

// fill CSR + pack per-node (beg,end) as int2
__global__ void k_fill(const int* __restrict__ src, const int* __restrict__ dst,
                       const int* __restrict__ off, const int* __restrict__ pos,
                       int* __restrict__ nbr, int2* __restrict__ bounds) {
    int e = blockIdx.x * 256 + threadIdx.x;
    if (e < N_NODES) bounds[e] = make_int2(off[e], off[e + 1]);
    if (e >= N_EDGES) return;
    int d = dst[e];
    nbr[off[d] + pos[e]] = src[e];
}

// ---- fused transform, LDS-staged X tile: B(bf16) = X@Wl ; C = X@Wr + bl ----
// LDS X tile, direct global weight loads (L1/L2-broadcast). NB=16: best
// occupancy point found (r9/r10 sweep); xform is at its issue/latency floor
// (LDS-weights, reg-prefetch, readlane, occupancy all null or worse).
template <int K, int NB>
__global__ __launch_bounds__(256) void k_xform3(
        const float* __restrict__ X, const float* __restrict__ Wl,
        const float* __restrict__ Wr, const float* __restrict__ bl,
        bf16* __restrict__ B, float* __restrict__ C) {
    __shared__ float tile[NB * K];
    const int NPW = NB / 4;
    int nodes0 = blockIdx.x * NB;
    {
        const int total4 = NB * K / 4;
        int nmax4 = (N_NODES - nodes0) * K / 4;
        const float4* Xg = (const float4*)(X + (long)nodes0 * K);
        float4* tg = (float4*)tile;
        for (int idx = threadIdx.x; idx < total4; idx += 256) {
            float4 v = make_float4(0.f, 0.f, 0.f, 0.f);
            if (idx < nmax4) v = Xg[idx];
            tg[idx] = v;
        }
    }
    __syncthreads();
    int wave = threadIdx.x >> 6, j = threadIdx.x & 63;
    long base = (long)nodes0 + wave * NPW;
    if (base >= N_NODES) return;
    float accB[NPW], accC[NPW];
    #pragma unroll
    for (int n = 0; n < NPW; n++) { accB[n] = 0.f; accC[n] = 0.f; }
    const float* Xs = tile + (wave * NPW) * K;
    for (int kc = 0; kc < K; kc += 4) {
        float wl0 = Wl[(kc + 0) * HD + j], wr0 = Wr[(kc + 0) * HD + j];
        float wl1 = Wl[(kc + 1) * HD + j], wr1 = Wr[(kc + 1) * HD + j];
        float wl2 = Wl[(kc + 2) * HD + j], wr2 = Wr[(kc + 2) * HD + j];
        float wl3 = Wl[(kc + 3) * HD + j], wr3 = Wr[(kc + 3) * HD + j];
        #pragma unroll
        for (int n = 0; n < NPW; n++) {
            float4 xv = *(const float4*)(Xs + n * K + kc);
            accB[n] = fmaf(xv.x, wl0, accB[n]);
            accC[n] = fmaf(xv.x, wr0, accC[n]);
            accB[n] = fmaf(xv.y, wl1, accB[n]);
            accC[n] = fmaf(xv.y, wr1, accC[n]);
            accB[n] = fmaf(xv.z, wl2, accB[n]);
            accC[n] = fmaf(xv.z, wr2, accC[n]);
            accB[n] = fmaf(xv.w, wl3, accB[n]);
            accC[n] = fmaf(xv.w, wr3, accC[n]);
        }
    }
    float bb = bl[j];
    int nact = (int)min((long)NPW, (long)N_NODES - base);
    for (int n = 0; n < nact; n++) {
        long i = base + n;
        B[i * HD + j] = __float2bfloat16(accB[n]);
        C[i * HD + j] = accC[n] + bb;
    }
}

__device__ __forceinline__ float bflo(unsigned u) { return __uint_as_float(u << 16); }
__device__ __forceinline__ float bfhi(unsigned u) { return __uint_as_float(u & 0xffff0000u); }

// ---- CSR gather, column-split half-passes, oct-row loads ----
// Grid = 2*GATHER_NB blocks; half h = blockIdx/GATHER_NB gathers columns
// 32h..32h+31 only. Active B-half = 3.2 MB -> fits a 4 MB per-XCD L2, so the
// random row reads become mostly L2 hits (r11 PMC: full-width pass missed
// ~51 MB to L3 at ~1.3 TB/s). Dispatch is roughly in-order so the halves run
// mostly sequentially; correctness never depends on it (B is read-only).
// Lane layout: 8 lanes x 8 B cover one 64-B row-half; 8 rows per wave-load.
// LAST=true: global-mean-pool the half into cb via device-scope atomics.
template <bool LAST>
__global__ __launch_bounds__(256) void k_gather(
        const int2* __restrict__ bounds, const int* __restrict__ nbr,
        const bf16* __restrict__ Bm, float* __restrict__ C,
        const int* __restrict__ batch, const float* __restrict__ invc,
        float* __restrict__ cb) {
    int h = blockIdx.x / GATHER_NB;
    int nb = blockIdx.x % GATHER_NB;
    int wid = threadIdx.x >> 6, lane = threadIdx.x & 63;
    int i = nb * 4 + wid;
    int q = lane >> 3, c = lane & 7;          // slot q in [0,8), byte-col c
    const uint2* B2 = (const uint2*)Bm;       // 16 uint2 per 64-col bf16 row
    const long hb = (long)h * 8 + c;          // uint2 offset within a row
    int2 be = bounds[i];
    int beg = be.x, end = be.y;
    float4 a0 = make_float4(0.f, 0.f, 0.f, 0.f);
    float4 a1 = make_float4(0.f, 0.f, 0.f, 0.f);
    float4 a2 = make_float4(0.f, 0.f, 0.f, 0.f);
    float4 a3 = make_float4(0.f, 0.f, 0.f, 0.f);
    for (int base = beg; base < end; base += 64) {
        int idx = base + lane;
        int nv = (idx < end) ? nbr[idx] : 0;
        int m = min(64, end - base);
        int tt = 0;
        for (; tt + 32 <= m; tt += 32) {       // 4 loads x 8 rows
            int n0 = __shfl(nv, tt + q);
            int n1 = __shfl(nv, tt + 8 + q);
            int n2 = __shfl(nv, tt + 16 + q);
            int n3 = __shfl(nv, tt + 24 + q);
            uint2 u0 = B2[(long)n0 * 16 + hb];
            uint2 u1 = B2[(long)n1 * 16 + hb];
            uint2 u2 = B2[(long)n2 * 16 + hb];
            uint2 u3 = B2[(long)n3 * 16 + hb];
            a0.x += bflo(u0.x); a0.y += bfhi(u0.x); a0.z += bflo(u0.y); a0.w += bfhi(u0.y);
            a1.x += bflo(u1.x); a1.y += bfhi(u1.x); a1.z += bflo(u1.y); a1.w += bfhi(u1.y);
            a2.x += bflo(u2.x); a2.y += bfhi(u2.x); a2.z += bflo(u2.y); a2.w += bfhi(u2.y);
            a3.x += bflo(u3.x); a3.y += bfhi(u3.x); a3.z += bflo(u3.y); a3.w += bfhi(u3.y);
        }
        for (; tt + 16 <= m; tt += 16) {       // 2 loads x 8 rows
            int n0 = __shfl(nv, tt + q);
            int n1 = __shfl(nv, tt + 8 + q);
            uint2 u0 = B2[(long)n0 * 16 + hb];
            uint2 u1 = B2[(long)n1 * 16 + hb];
            a0.x += bflo(u0.x); a0.y += bfhi(u0.x); a0.z += bflo(u0.y); a0.w += bfhi(u0.y);
            a1.x += bflo(u1.x); a1.y += bfhi(u1.x); a1.z += bflo(u1.y); a1.w += bfhi(u1.y);
        }
        for (; tt < m; tt += 8) {              // guarded tail
            int n0 = __shfl(nv, tt + q);
            if (tt + q < m) {
                uint2 u0 = B2[(long)n0 * 16 + hb];
                a0.x += bflo(u0.x); a0.y += bfhi(u0.x);
                a0.z += bflo(u0.y); a0.w += bfhi(u0.y);
            }
        }
    }
    float4 s;
    s.x = (a0.x + a1.x) + (a2.x + a3.x);
    s.y = (a0.y + a1.y) + (a2.y + a3.y);
    s.z = (a0.z + a1.z) + (a2.z + a3.z);
    s.w = (a0.w + a1.w) + (a2.w + a3.w);
    s.x += __shfl_xor(s.x, 8); s.x += __shfl_xor(s.x, 16); s.x += __shfl_xor(s.x, 32);
    s.y += __shfl_xor(s.y, 8); s.y += __shfl_xor(s.y, 16); s.y += __shfl_xor(s.y, 32);
    s.z += __shfl_xor(s.z, 8); s.z += __shfl_xor(s.z, 16); s.z += __shfl_xor(s.z, 32);
    s.w += __shfl_xor(s.w, 8); s.w += __shfl_xor(s.w, 16); s.w += __shfl_xor(s.w, 32);
    int deg = end - beg;
    float inv = 1.0f / (float)max(deg, 1);
    if (!LAST) {
        if (lane < 8) {
            float4* Cp = (float4*)(C + (long)i * HD + h * 32 + 4 * lane);
            float4 cur = *Cp;
            cur.x += s.x * inv;
            cur.y += s.y * inv;
            cur.z += s.z * inv;
            cur.w += s.w * inv;
            *Cp = cur;
        }
    } else {
        // fused global-mean-pool of this half: cross-wave reduce in LDS,
        // then 32 atomics (all 4 waves of the block share the same h).
        __shared__ float red[4][32];
        __shared__ int gid[4];
        if (lane < 8) {
            const float4 cur = *(const float4*)(C + (long)i * HD + h * 32 + 4 * lane);
            red[wid][4 * lane + 0] = cur.x + s.x * inv;
            red[wid][4 * lane + 1] = cur.y + s.y * inv;
            red[wid][4 * lane + 2] = cur.z + s.z * inv;
            red[wid][4 * lane + 3] = cur.w + s.w * inv;
        }
        if (lane == 0) gid[wid] = batch[i];
        __syncthreads();
        if (wid == 0 && lane < 32) {
            int g0 = gid[0], g1 = gid[1], g2 = gid[2], g3 = gid[3];
            float v0 = red[0][lane], v1 = red[1][lane];
            float v2 = red[2][lane], v3 = red[3][lane];
            int col = h * 32 + lane;
            if (g0 == g3) {   // sorted batch: g0==g3 implies all equal
                atomicAdd(&cb[g0 * HD + col],
                          ((v0 + v1) + (v2 + v3)) * invc[g0]);
            } else {
                atomicAdd(&cb[g0 * HD + col], v0 * invc[g0]);
                atomicAdd(&cb[g1 * HD + col], v1 * invc[g1]);
                atomicAdd(&cb[g2 * HD + col], v2 * invc[g2]);
                atomicAdd(&cb[g3 * HD + col], v3 * invc[g3]);
            }
        }
    }
}

// ---------------- fused head, row-partitioned, LDS-staged weights ----------
// Block r owns graphs 4r..4r+3 end-to-end; intermediates stay in LDS.
// Only BN column-statistics cross blocks (device-scope atomics).
__device__ __forceinline__ void gbar(int* bar, int round) {
    __syncthreads();
    if (threadIdx.x == 0) {
        __hip_atomic_fetch_add(bar, 1, __ATOMIC_ACQ_REL, __HIP_MEMORY_SCOPE_AGENT);
        int target = round * NB_HEAD;
        while (__hip_atomic_load(bar, __ATOMIC_ACQUIRE, __HIP_MEMORY_SCOPE_AGENT) < target) {}
    }
    __syncthreads();
}

__device__ __forceinline__ float ag_load(const float* p) {
    return __hip_atomic_load(p, __ATOMIC_RELAXED, __HIP_MEMORY_SCOPE_AGENT);
}

// copy NF floats (NF % 1024 == 0) global->LDS as float4, fully unrolled
template <int NF>
__device__ __forceinline__ void stage4(float* __restrict__ s, const float* __restrict__ g) {
    const float4* g4 = (const float4*)g;
    float4* s4 = (float4*)s;
    #pragma unroll
    for (int i = 0; i < NF / 1024; i++)
        s4[i * 256 + threadIdx.x] = g4[i * 256 + threadIdx.x];
}

__global__ __launch_bounds__(256) void k_head(
        int* bar, float* __restrict__ gstat,
        const float* __restrict__ l1w, const float* __restrict__ l1b,
        const float* __restrict__ g1, const float* __restrict__ be1,
        const float* __restrict__ l2w, const float* __restrict__ l2b,
        const float* __restrict__ g2, const float* __restrict__ be2,
        const float* __restrict__ l3w, const float* __restrict__ l3b,
        const float* __restrict__ g3, const float* __restrict__ be3,
        const float* __restrict__ w4, const float* __restrict__ b4,
        const float* __restrict__ cb, float* __restrict__ out) {
    __shared__ float WB[32768];    // 128 KB weight staging buffer
    __shared__ float A1[4][64];    // cb rows (lin1 input)
    __shared__ float A2[4][256];   // lin1 output
    __shared__ float A3[4][128];   // lin2 output
    __shared__ float M3[4][64];    // lin3 output
    __shared__ float W4[640];      // lin4 weights
    float* gs1 = gstat;            // [256] lin1 col sums
    float* gq1 = gstat + 256;      // [256]
    float* gs2 = gstat + 512;      // [128]
    float* gq2 = gstat + 640;      // [128]
    float* gs3 = gstat + 768;      // [64]
    float* gq3 = gstat + 832;      // [64]
    int t = threadIdx.x;
    int r0 = blockIdx.x * 4;       // first graph row owned by this block

    // phase 0: stage lin1_w (64 KB) into WB[16384..32768), w4, cb rows
    {
        int r = t >> 6, lane = t & 63;
        A1[r][lane] = cb[(r0 + r) * HD + lane];
    }
    if (t < 160) ((float4*)W4)[t] = ((const float4*)w4)[t];
    stage4<16384>(WB + 16384, l1w);
    __syncthreads();

    // ---- lin1: K=64 -> N=256; thread t owns column t for all 4 rows ----
    float v1[4];
    {
        float bj = l1b[t];
        v1[0] = bj; v1[1] = bj; v1[2] = bj; v1[3] = bj;
        const float* Wp = WB + 16384;
        #pragma unroll 16
        for (int k = 0; k < 64; k++) {
            float w = Wp[k * 256 + t];
            v1[0] = fmaf(A1[0][k], w, v1[0]);
            v1[1] = fmaf(A1[1][k], w, v1[1]);
            v1[2] = fmaf(A1[2][k], w, v1[2]);
            v1[3] = fmaf(A1[3][k], w, v1[3]);
        }
        float s = (v1[0] + v1[1]) + (v1[2] + v1[3]);
        float q = (v1[0] * v1[0] + v1[1] * v1[1]) + (v1[2] * v1[2] + v1[3] * v1[3]);
        atomicAdd(&gs1[t], s);
        atomicAdd(&gq1[t], q);
    }
    __syncthreads();                 // all waves done reading WB hi
    stage4<32768>(WB, l2w);          // full lin2_w; latency hides under barrier
    gbar(bar, 1);
    {
        float S = ag_load(&gs1[t]), Q = ag_load(&gq1[t]);
        float mean = S * (1.0f / NUM_GRAPHS);
        float var = Q * (1.0f / NUM_GRAPHS) - mean * mean;
        float sc = rsqrtf(fmaxf(var, 0.f) + EPS) * g1[t];
        float sh = be1[t];
        #pragma unroll
        for (int r = 0; r < 4; r++)
            A2[r][t] = tanhf((v1[r] - mean) * sc + sh);
    }
    __syncthreads();                 // A2 ready (WB ready via gbar's barrier)

    // ---- lin2: K=256 -> N=128; thread = (col j2, rowpair rq2) ----
    float v2[2];
    int j2 = t & 127, rq2 = t >> 7;
    {
        float bj = l2b[j2];
        v2[0] = bj; v2[1] = bj;
        const float* a0 = A2[2 * rq2 + 0];
        const float* a1 = A2[2 * rq2 + 1];
        #pragma unroll 16
        for (int k = 0; k < 256; k++) {
            float w = WB[k * 128 + j2];
            v2[0] = fmaf(a0[k], w, v2[0]);
            v2[1] = fmaf(a1[k], w, v2[1]);
        }
        atomicAdd(&gs2[j2], v2[0] + v2[1]);
        atomicAdd(&gq2[j2], v2[0] * v2[0] + v2[1] * v2[1]);
    }
    __syncthreads();                 // all waves done reading WB
    stage4<8192>(WB, l3w);           // lin3_w; latency hides under barrier
    gbar(bar, 2);
    {
        float S = ag_load(&gs2[j2]), Q = ag_load(&gq2[j2]);
        float mean = S * (1.0f / NUM_GRAPHS);
        float var = Q * (1.0f / NUM_GRAPHS) - mean * mean;
        float sc = rsqrtf(fmaxf(var, 0.f) + EPS) * g2[j2];
        float sh = be2[j2];
        A3[2 * rq2 + 0][j2] = tanhf((v2[0] - mean) * sc + sh);
        A3[2 * rq2 + 1][j2] = tanhf((v2[1] - mean) * sc + sh);
    }
    __syncthreads();                 // A3 ready (WB ready via gbar's barrier)

    // ---- lin3: K=128 -> N=64; thread = (col j3, row rq3) ----
    float v3;
    int j3 = t & 63, rq3 = t >> 6;
    {
        float bj = l3b[j3];
        v3 = bj;
        const float* a = A3[rq3];
        #pragma unroll 16
        for (int k = 0; k < 128; k++) {
            float w = WB[k * 64 + j3];
            v3 = fmaf(a[k], w, v3);
        }
        atomicAdd(&gs3[j3], v3);
        atomicAdd(&gq3[j3], v3 * v3);
    }
    gbar(bar, 3);
    {
        float S = ag_load(&gs3[j3]), Q = ag_load(&gq3[j3]);
        float mean = S * (1.0f / NUM_GRAPHS);
        float var = Q * (1.0f / NUM_GRAPHS) - mean * mean;
        float sc = rsqrtf(fmaxf(var, 0.f) + EPS) * g3[j3];
        float sh = be3[j3];
        M3[rq3][j3] = tanhf((v3 - mean) * sc + sh);
    }
    __syncthreads();

    // ---- lin4: 4 rows x 10 outputs, all LDS-local ----
    if (t < 40) {
        int q = t / 10, jf = t % 10;
        const float* rp = M3[q];
        float s = b4[jf];
        #pragma unroll
        for (int k = 0; k < 64; k++) s = fmaf(rp[k], W4[k * 10 + jf], s);
        out[(r0 + q) * 10 + jf] = s;
    }
}

extern "C" void kernel_launch(void* const* d_in, const int* in_sizes, int n_in,
                              void* d_out, int out_size, void* d_ws, size_t ws_size,
                              hipStream_t stream) {
    const float* x     = (const float*)d_in[0];
    const int*   ei    = (const int*) d_in[1];
    const int*   batch = (const int*) d_in[2];
    const float *W1l = (const float*)d_in[3],  *b1l = (const float*)d_in[4],  *W1r = (const float*)d_in[5];
    const float *W2l = (const float*)d_in[6],  *b2l = (const float*)d_in[7],  *W2r = (const float*)d_in[8];
    const float *W3l = (const float*)d_in[9],  *b3l = (const float*)d_in[10], *W3r = (const float*)d_in[11];
    const float *lin1_w = (const float*)d_in[12], *lin1_b = (const float*)d_in[13];
    const float *g1 = (const float*)d_in[14], *be1 = (const float*)d_in[15];
    const float *lin2_w = (const float*)d_in[16], *lin2_b = (const float*)d_in[17];
    const float *g2 = (const float*)d_in[18], *be2 = (const float*)d_in[19];
    const float *lin3_w = (const float*)d_in[20], *lin3_b = (const float*)d_in[21];
    const float *g3 = (const float*)d_in[22], *be3 = (const float*)d_in[23];
    const float *lin4_w = (const float*)d_in[24], *lin4_b = (const float*)d_in[25];

    const int* srcp = ei;
    const int* dstp = ei + N_EDGES;

    // ---- workspace layout ----
    const long NF = (long)N_NODES * HD;              // 3,200,000
    char* wsb  = (char*)d_ws;
    int*  cnti = (int*)wsb;                          // 50,048
    int*  bar  = cnti + 50048;                       // 8
    float* gstat = (float*)(bar + 8);                // 896 (zeroed with cnti)
    int*  pos  = (int*)(gstat + 896);                // 800,000
    int*  off  = pos  + 800000;                      // 50,056
    int*  nbr  = off  + 50056;                       // 800,000
    int*  bsum = nbr  + 800000;                      // 256
    int*  gb   = bsum + 256;                         // 264 (257 used)
    float* invc = (float*)(gb + 264);                // 256
    int2* bounds = (int2*)(invc + 256);              // 50,000 int2 (8B-aligned)
    bf16* B    = (bf16*)(bounds + 50000);            // 3,200,000 bf16
    float* H1  = (float*)(B + NF);                   // 3,200,000
    float* H2  = H1  + NF;                           // 3,200,000
    float* cb  = H2  + NF;                           // 16,384
    float* endp= cb  + NUM_GRAPHS * HD;

    const size_t NEED = (size_t)((char*)endp - wsb);
    if (ws_size < NEED) {
        k_diag<<<(out_size + 255) / 256, 256, 0, stream>>>((float*)d_out, out_size,
                                                           (float)(ws_size >> 20));
        return;
    }

    const int TB = 256;
    const int gNE = (N_EDGES + TB - 1) / TB;
    const int gX16 = (N_NODES + 15) / 16;             // 3125 (all xforms)
    const int gGA = 2 * GATHER_NB;                    // 25000 (two half-passes)

    hipMemsetAsync(cnti, 0, (50048 + 8 + 896) * sizeof(int), stream);
    hipMemsetAsync(cb, 0, NUM_GRAPHS * HD * sizeof(float), stream);

    // ---- CSR build (+ graph bounds + packed node bounds) ----
    k_count<<<gNE, TB, 0, stream>>>(dstp, batch, cnti, pos, gb);
    k_scan1<<<SCAN_NB, TB, 0, stream>>>(cnti, off, bsum);
    k_scan3<<<SCAN_NB, TB, 0, stream>>>(off, bsum, gb, invc);
    k_fill<<<gNE, TB, 0, stream>>>(srcp, dstp, off, pos, nbr, bounds);

    // ---- SAGE layers (bf16 messages, column-split oct-row gather) ----
    k_xform3<IN_DIM, 16><<<gX16, TB, 0, stream>>>(x, W1l, W1r, b1l, B, H1);
    k_gather<false><<<gGA, TB, 0, stream>>>(bounds, nbr, B, H1, batch, invc, cb);
    k_xform3<HD, 16><<<gX16, TB, 0, stream>>>(H1, W2l, W2r, b2l, B, H2);
    k_gather<false><<<gGA, TB, 0, stream>>>(bounds, nbr, B, H2, batch, invc, cb);
    k_xform3<HD, 16><<<gX16, TB, 0, stream>>>(H2, W3l, W3r, b3l, B, H1);
    // last gather: fused global-mean-pool into cb (H1 never written back)
    k_gather<true><<<gGA, TB, 0, stream>>>(bounds, nbr, B, H1, batch, invc, cb);

    // ---- fused head: row-partitioned, LDS-staged weights ----
    k_head<<<NB_HEAD, TB, 0, stream>>>(bar, gstat,
                                       lin1_w, lin1_b, g1, be1,
                                       lin2_w, lin2_b, g2, be2,
                                       lin3_w, lin3_b, g3, be3,
                                       lin4_w, lin4_b,
                                       cb, (float*)d_out);
}

// Round 14
// 347.286 us; speedup vs baseline: 1.1480x; 1.1480x over previous
//
#include <hip/hip_runtime.h>
#include <hip/hip_bf16.h>

#define N_NODES   50000
#define N_EDGES   800000
#define NUM_GRAPHS 256
#define IN_DIM    128
#define HD        64
#define EPS       1e-5f
#define SCAN_NB   196      // ceil(50000/256)
#define NB_HEAD   64       // head kernel grid (must be <= CU count for co-residency)

typedef __hip_bfloat16 bf16;

// ---------------- diagnostics ----------------
__global__ void k_diag(float* __restrict__ out, int n, float v) {
    int t = blockIdx.x * 256 + threadIdx.x;
    if (t < n) out[t] = v;
}

// ---------------- CSR build ----------------
__global__ void k_scan1(const int* __restrict__ cnti, int* __restrict__ off,
                        int* __restrict__ bsum) {
    __shared__ int wsum[4];
    int idx = blockIdx.x * 256 + threadIdx.x;
    int lane = threadIdx.x & 63, wid = threadIdx.x >> 6;
    int v = (idx < N_NODES) ? cnti[idx] : 0;
    int s = v;
    #pragma unroll
    for (int o = 1; o < 64; o <<= 1) {
        int u = __shfl_up(s, o);
        if (lane >= o) s += u;
    }
    if (lane == 63) wsum[wid] = s;
    __syncthreads();
    int wbase = 0;
    #pragma unroll
    for (int w = 0; w < 4; w++) wbase += (w < wid) ? wsum[w] : 0;
    if (idx < N_NODES) off[idx] = wbase + s - v;
    if (threadIdx.x == 255) bsum[blockIdx.x] = wbase + s;
}

// scan finalize + bounds pack + invc + cb zero (folds one memset dispatch)
__global__ void k_scan3(int* __restrict__ off, const int* __restrict__ bsum,
                        const int* __restrict__ cnti, const int* __restrict__ gb,
                        float* __restrict__ invc, int2* __restrict__ bounds,
                        float* __restrict__ cb) {
    __shared__ int wsum[4];
    __shared__ int spre;
    int lane = threadIdx.x & 63, wid = threadIdx.x >> 6;
    int v = (threadIdx.x < blockIdx.x) ? bsum[threadIdx.x] : 0;
    #pragma unroll
    for (int o = 32; o > 0; o >>= 1) v += __shfl_down(v, o);
    if (lane == 0) wsum[wid] = v;
    __syncthreads();
    if (threadIdx.x == 0) spre = wsum[0] + wsum[1] + wsum[2] + wsum[3];
    __syncthreads();
    int pre = spre;
    int idx = blockIdx.x * 256 + threadIdx.x;
    if (idx < N_NODES) {
        int ofin = off[idx] + pre;
        off[idx] = ofin;
        bounds[idx] = make_int2(ofin, ofin + cnti[idx]);
    } else if (idx == N_NODES) {
        off[N_NODES] = N_EDGES;
    }
    // zero cb: 16384 floats over the first 64 blocks (ready long before gathers)
    if (blockIdx.x < 64) cb[blockIdx.x * 256 + threadIdx.x] = 0.f;
    // per-graph 1/count for fused pooling (gb ready since xform1's count phase)
    if (blockIdx.x == 0 && threadIdx.x < NUM_GRAPHS) {
        int c0 = gb[threadIdx.x], c1 = gb[threadIdx.x + 1];
        invc[threadIdx.x] = 1.0f / (float)max(c1 - c0, 1);
    }
}

__global__ void k_fill(const int* __restrict__ src, const int* __restrict__ dst,
                       const int* __restrict__ off, const int* __restrict__ pos,
                       int* __restrict__ nbr) {
    int e = blockIdx.x * 256 + threadIdx.x;
    if (e >= N_EDGES) return;
    int d = dst[e];
    nbr[off[d] + pos[e]] = src[e];
}

// ---- fused transform, LDS-staged X tile: B(bf16) = X@Wl ; C = X@Wr + bl ----
// NB=16: best occupancy point (r9/r10 sweep); the inner loop is at its
// issue/latency floor (LDS-weights, reg-prefetch, readlane, occupancy all
// null or worse). CNT=true (layer 1 only): the CSR count phase is merged in
// -- grid is exactly 3125x256 = one thread per edge -- its atomic traffic
// retires under the transform's FMA work, deleting the k_count dispatch.
template <int K, int NB, bool CNT>
__global__ __launch_bounds__(256) void k_xform3(
        const float* __restrict__ X, const float* __restrict__ Wl,
        const float* __restrict__ Wr, const float* __restrict__ bl,
        bf16* __restrict__ B, float* __restrict__ C,
        const int* __restrict__ dst, const int* __restrict__ batch,
        int* __restrict__ cnti, int* __restrict__ pos, int* __restrict__ gb) {
    if (CNT) {
        int e = blockIdx.x * 256 + threadIdx.x;
        if (e < N_EDGES) pos[e] = atomicAdd(&cnti[dst[e]], 1);
        // graph bounds: gb[g] = first node index with batch >= g (sorted batch)
        if (e < N_NODES) {
            int bg = batch[e];
            int bnext = (e + 1 < N_NODES) ? batch[e + 1] : NUM_GRAPHS;
            if (e == 0) {
                for (int g = 0; g <= bg; ++g) gb[g] = 0;
            }
            for (int g = bg + 1; g <= bnext; ++g) gb[g] = e + 1;
        }
    }
    __shared__ float tile[NB * K];
    const int NPW = NB / 4;
    int nodes0 = blockIdx.x * NB;
    {
        const int total4 = NB * K / 4;
        int nmax4 = (N_NODES - nodes0) * K / 4;
        const float4* Xg = (const float4*)(X + (long)nodes0 * K);
        float4* tg = (float4*)tile;
        for (int idx = threadIdx.x; idx < total4; idx += 256) {
            float4 v = make_float4(0.f, 0.f, 0.f, 0.f);
            if (idx < nmax4) v = Xg[idx];
            tg[idx] = v;
        }
    }
    __syncthreads();
    int wave = threadIdx.x >> 6, j = threadIdx.x & 63;
    long base = (long)nodes0 + wave * NPW;
    if (base >= N_NODES) return;
    float accB[NPW], accC[NPW];
    #pragma unroll
    for (int n = 0; n < NPW; n++) { accB[n] = 0.f; accC[n] = 0.f; }
    const float* Xs = tile + (wave * NPW) * K;
    for (int kc = 0; kc < K; kc += 4) {
        float wl0 = Wl[(kc + 0) * HD + j], wr0 = Wr[(kc + 0) * HD + j];
        float wl1 = Wl[(kc + 1) * HD + j], wr1 = Wr[(kc + 1) * HD + j];
        float wl2 = Wl[(kc + 2) * HD + j], wr2 = Wr[(kc + 2) * HD + j];
        float wl3 = Wl[(kc + 3) * HD + j], wr3 = Wr[(kc + 3) * HD + j];
        #pragma unroll
        for (int n = 0; n < NPW; n++) {
            float4 xv = *(const float4*)(Xs + n * K + kc);
            accB[n] = fmaf(xv.x, wl0, accB[n]);
            accC[n] = fmaf(xv.x, wr0, accC[n]);
            accB[n] = fmaf(xv.y, wl1, accB[n]);
            accC[n] = fmaf(xv.y, wr1, accC[n]);
            accB[n] = fmaf(xv.z, wl2, accB[n]);
            accC[n] = fmaf(xv.z, wr2, accC[n]);
            accB[n] = fmaf(xv.w, wl3, accB[n]);
            accC[n] = fmaf(xv.w, wr3, accC[n]);
        }
    }
    float bb = bl[j];
    int nact = (int)min((long)NPW, (long)N_NODES - base);
    for (int n = 0; n < nact; n++) {
        long i = base + n;
        B[i * HD + j] = __float2bfloat16(accB[n]);
        C[i * HD + j] = accC[n] + bb;
    }
}

__device__ __forceinline__ float bflo(unsigned u) { return __uint_as_float(u << 16); }
__device__ __forceinline__ float bfhi(unsigned u) { return __uint_as_float(u & 0xffff0000u); }

// ---- CSR gather, quad-row (4 neighbor rows per wave-load, uint2/lane) ----
// 16 lanes x 8 B cover one 128 B row; quarter q = lane>>4 owns row slot q.
// Random-access L2/L3-BW-bound (~51 MB L2-miss/dispatch); r11 (added work)
// and r13 (column split: fetch doubled to 92 MB) both regressed -- this is
// the measured floor for the structure.
// LAST=true: fuse the global mean pool: accumulate (C_row + mean_aggr) *
// invc[batch[i]] into cb via device-scope atomics.
template <bool LAST>
__global__ void k_gather(const int2* __restrict__ bounds, const int* __restrict__ nbr,
                         const bf16* __restrict__ Bm, float* __restrict__ C,
                         const int* __restrict__ batch, const float* __restrict__ invc,
                         float* __restrict__ cb) {
    int t = blockIdx.x * 256 + threadIdx.x;
    int i = t >> 6, lane = t & 63;
    if (!LAST && i >= N_NODES) return;
    int q = lane >> 4, c2 = lane & 15;
    int wid = threadIdx.x >> 6;
    const uint2* B2 = (const uint2*)Bm;       // 16 uint2 per 64-col bf16 row
    int2 be = bounds[i];
    int beg = be.x, end = be.y;
    float4 a0 = make_float4(0.f, 0.f, 0.f, 0.f);
    float4 a1 = make_float4(0.f, 0.f, 0.f, 0.f);
    float4 a2 = make_float4(0.f, 0.f, 0.f, 0.f);
    float4 a3 = make_float4(0.f, 0.f, 0.f, 0.f);
    for (int base = beg; base < end; base += 64) {
        int idx = base + lane;
        int nv = (idx < end) ? nbr[idx] : 0;
        int m = min(64, end - base);
        int tt = 0;
        for (; tt + 16 <= m; tt += 16) {
            int n0 = __shfl(nv, tt + 0 + q);
            int n1 = __shfl(nv, tt + 4 + q);
            int n2 = __shfl(nv, tt + 8 + q);
            int n3 = __shfl(nv, tt + 12 + q);
            uint2 u0 = B2[(long)n0 * 16 + c2];
            uint2 u1 = B2[(long)n1 * 16 + c2];
            uint2 u2 = B2[(long)n2 * 16 + c2];
            uint2 u3 = B2[(long)n3 * 16 + c2];
            a0.x += bflo(u0.x); a0.y += bfhi(u0.x); a0.z += bflo(u0.y); a0.w += bfhi(u0.y);
            a1.x += bflo(u1.x); a1.y += bfhi(u1.x); a1.z += bflo(u1.y); a1.w += bfhi(u1.y);
            a2.x += bflo(u2.x); a2.y += bfhi(u2.x); a2.z += bflo(u2.y); a2.w += bfhi(u2.y);
            a3.x += bflo(u3.x); a3.y += bfhi(u3.x); a3.z += bflo(u3.y); a3.w += bfhi(u3.y);
        }
        for (; tt < m; tt += 4) {
            int n0 = __shfl(nv, tt + q);
            if (tt + q < m) {
                uint2 u0 = B2[(long)n0 * 16 + c2];
                a0.x += bflo(u0.x); a0.y += bfhi(u0.x);
                a0.z += bflo(u0.y); a0.w += bfhi(u0.y);
            }
        }
    }
    float4 s;
    s.x = (a0.x + a1.x) + (a2.x + a3.x);
    s.y = (a0.y + a1.y) + (a2.y + a3.y);
    s.z = (a0.z + a1.z) + (a2.z + a3.z);
    s.w = (a0.w + a1.w) + (a2.w + a3.w);
    s.x += __shfl_xor(s.x, 16); s.x += __shfl_xor(s.x, 32);
    s.y += __shfl_xor(s.y, 16); s.y += __shfl_xor(s.y, 32);
    s.z += __shfl_xor(s.z, 16); s.z += __shfl_xor(s.z, 32);
    s.w += __shfl_xor(s.w, 16); s.w += __shfl_xor(s.w, 32);
    if (!LAST) {
        if (lane < 16) {
            int deg = end - beg;
            float inv = 1.0f / (float)max(deg, 1);
            float4* Cp = (float4*)(C + (long)i * HD + 4 * lane);
            float4 cur = *Cp;
            cur.x += s.x * inv;
            cur.y += s.y * inv;
            cur.z += s.z * inv;
            cur.w += s.w * inv;
            *Cp = cur;
        }
    } else {
        // fused global-mean-pool: block covers 4 consecutive nodes (sorted batch
        // -> usually same graph); cross-wave reduce in LDS, then 64 atomics.
        __shared__ float red[4][64];
        __shared__ int gid[4];
        if (lane < 16) {
            int deg = end - beg;
            float inv = 1.0f / (float)max(deg, 1);
            const float4 cur = *(const float4*)(C + (long)i * HD + 4 * lane);
            red[wid][4 * lane + 0] = cur.x + s.x * inv;
            red[wid][4 * lane + 1] = cur.y + s.y * inv;
            red[wid][4 * lane + 2] = cur.z + s.z * inv;
            red[wid][4 * lane + 3] = cur.w + s.w * inv;
        }
        if (lane == 0) gid[wid] = batch[i];
        __syncthreads();
        if (wid == 0) {
            int g0 = gid[0], g1 = gid[1], g2 = gid[2], g3 = gid[3];
            float v0 = red[0][lane], v1 = red[1][lane];
            float v2 = red[2][lane], v3 = red[3][lane];
            if (g0 == g3) {   // sorted batch: g0==g3 implies all equal
                atomicAdd(&cb[g0 * HD + lane],
                          ((v0 + v1) + (v2 + v3)) * invc[g0]);
            } else {
                atomicAdd(&cb[g0 * HD + lane], v0 * invc[g0]);
                atomicAdd(&cb[g1 * HD + lane], v1 * invc[g1]);
                atomicAdd(&cb[g2 * HD + lane], v2 * invc[g2]);
                atomicAdd(&cb[g3 * HD + lane], v3 * invc[g3]);
            }
        }
    }
}

// ---------------- fused head, row-partitioned, LDS-staged weights ----------
// Block r owns graphs 4r..4r+3 end-to-end; intermediates stay in LDS.
// Only BN column-statistics cross blocks (device-scope atomics).
__device__ __forceinline__ void gbar(int* bar, int round) {
    __syncthreads();
    if (threadIdx.x == 0) {
        __hip_atomic_fetch_add(bar, 1, __ATOMIC_ACQ_REL, __HIP_MEMORY_SCOPE_AGENT);
        int target = round * NB_HEAD;
        while (__hip_atomic_load(bar, __ATOMIC_ACQUIRE, __HIP_MEMORY_SCOPE_AGENT) < target) {}
    }
    __syncthreads();
}

__device__ __forceinline__ float ag_load(const float* p) {
    return __hip_atomic_load(p, __ATOMIC_RELAXED, __HIP_MEMORY_SCOPE_AGENT);
}

// copy NF floats (NF % 1024 == 0) global->LDS as float4, fully unrolled
template <int NF>
__device__ __forceinline__ void stage4(float* __restrict__ s, const float* __restrict__ g) {
    const float4* g4 = (const float4*)g;
    float4* s4 = (float4*)s;
    #pragma unroll
    for (int i = 0; i < NF / 1024; i++)
        s4[i * 256 + threadIdx.x] = g4[i * 256 + threadIdx.x];
}

__global__ __launch_bounds__(256) void k_head(
        int* bar, float* __restrict__ gstat,
        const float* __restrict__ l1w, const float* __restrict__ l1b,
        const float* __restrict__ g1, const float* __restrict__ be1,
        const float* __restrict__ l2w, const float* __restrict__ l2b,
        const float* __restrict__ g2, const float* __restrict__ be2,
        const float* __restrict__ l3w, const float* __restrict__ l3b,
        const float* __restrict__ g3, const float* __restrict__ be3,
        const float* __restrict__ w4, const float* __restrict__ b4,
        const float* __restrict__ cb, float* __restrict__ out) {
    __shared__ float WB[32768];    // 128 KB weight staging buffer
    __shared__ float A1[4][64];    // cb rows (lin1 input)
    __shared__ float A2[4][256];   // lin1 output
    __shared__ float A3[4][128];   // lin2 output
    __shared__ float M3[4][64];    // lin3 output
    __shared__ float W4[640];      // lin4 weights
    float* gs1 = gstat;            // [256] lin1 col sums
    float* gq1 = gstat + 256;      // [256]
    float* gs2 = gstat + 512;      // [128]
    float* gq2 = gstat + 640;      // [128]
    float* gs3 = gstat + 768;      // [64]
    float* gq3 = gstat + 832;      // [64]
    int t = threadIdx.x;
    int r0 = blockIdx.x * 4;       // first graph row owned by this block

    // phase 0: stage lin1_w (64 KB) into WB[16384..32768), w4, cb rows
    {
        int r = t >> 6, lane = t & 63;
        A1[r][lane] = cb[(r0 + r) * HD + lane];
    }
    if (t < 160) ((float4*)W4)[t] = ((const float4*)w4)[t];
    stage4<16384>(WB + 16384, l1w);
    __syncthreads();

    // ---- lin1: K=64 -> N=256; thread t owns column t for all 4 rows ----
    float v1[4];
    {
        float bj = l1b[t];
        v1[0] = bj; v1[1] = bj; v1[2] = bj; v1[3] = bj;
        const float* Wp = WB + 16384;
        #pragma unroll 16
        for (int k = 0; k < 64; k++) {
            float w = Wp[k * 256 + t];
            v1[0] = fmaf(A1[0][k], w, v1[0]);
            v1[1] = fmaf(A1[1][k], w, v1[1]);
            v1[2] = fmaf(A1[2][k], w, v1[2]);
            v1[3] = fmaf(A1[3][k], w, v1[3]);
        }
        float s = (v1[0] + v1[1]) + (v1[2] + v1[3]);
        float q = (v1[0] * v1[0] + v1[1] * v1[1]) + (v1[2] * v1[2] + v1[3] * v1[3]);
        atomicAdd(&gs1[t], s);
        atomicAdd(&gq1[t], q);
    }
    __syncthreads();                 // all waves done reading WB hi
    stage4<32768>(WB, l2w);          // full lin2_w; latency hides under barrier
    gbar(bar, 1);
    {
        float S = ag_load(&gs1[t]), Q = ag_load(&gq1[t]);
        float mean = S * (1.0f / NUM_GRAPHS);
        float var = Q * (1.0f / NUM_GRAPHS) - mean * mean;
        float sc = rsqrtf(fmaxf(var, 0.f) + EPS) * g1[t];
        float sh = be1[t];
        #pragma unroll
        for (int r = 0; r < 4; r++)
            A2[r][t] = tanhf((v1[r] - mean) * sc + sh);
    }
    __syncthreads();                 // A2 ready (WB ready via gbar's barrier)

    // ---- lin2: K=256 -> N=128; thread = (col j2, rowpair rq2) ----
    float v2[2];
    int j2 = t & 127, rq2 = t >> 7;
    {
        float bj = l2b[j2];
        v2[0] = bj; v2[1] = bj;
        const float* a0 = A2[2 * rq2 + 0];
        const float* a1 = A2[2 * rq2 + 1];
        #pragma unroll 16
        for (int k = 0; k < 256; k++) {
            float w = WB[k * 128 + j2];
            v2[0] = fmaf(a0[k], w, v2[0]);
            v2[1] = fmaf(a1[k], w, v2[1]);
        }
        atomicAdd(&gs2[j2], v2[0] + v2[1]);
        atomicAdd(&gq2[j2], v2[0] * v2[0] + v2[1] * v2[1]);
    }
    __syncthreads();                 // all waves done reading WB
    stage4<8192>(WB, l3w);           // lin3_w; latency hides under barrier
    gbar(bar, 2);
    {
        float S = ag_load(&gs2[j2]), Q = ag_load(&gq2[j2]);
        float mean = S * (1.0f / NUM_GRAPHS);
        float var = Q * (1.0f / NUM_GRAPHS) - mean * mean;
        float sc = rsqrtf(fmaxf(var, 0.f) + EPS) * g2[j2];
        float sh = be2[j2];
        A3[2 * rq2 + 0][j2] = tanhf((v2[0] - mean) * sc + sh);
        A3[2 * rq2 + 1][j2] = tanhf((v2[1] - mean) * sc + sh);
    }
    __syncthreads();                 // A3 ready (WB ready via gbar's barrier)

    // ---- lin3: K=128 -> N=64; thread = (col j3, row rq3) ----
    float v3;
    int j3 = t & 63, rq3 = t >> 6;
    {
        float bj = l3b[j3];
        v3 = bj;
        const float* a = A3[rq3];
        #pragma unroll 16
        for (int k = 0; k < 128; k++) {
            float w = WB[k * 64 + j3];
            v3 = fmaf(a[k], w, v3);
        }
        atomicAdd(&gs3[j3], v3);
        atomicAdd(&gq3[j3], v3 * v3);
    }
    gbar(bar, 3);
    {
        float S = ag_load(&gs3[j3]), Q = ag_load(&gq3[j3]);
        float mean = S * (1.0f / NUM_GRAPHS);
        float var = Q * (1.0f / NUM_GRAPHS) - mean * mean;
        float sc = rsqrtf(fmaxf(var, 0.f) + EPS) * g3[j3];
        float sh = be3[j3];
        M3[rq3][j3] = tanhf((v3 - mean) * sc + sh);
    }
    __syncthreads();

    // ---- lin4: 4 rows x 10 outputs, all LDS-local ----
    if (t < 40) {
        int q = t / 10, jf = t % 10;
        const float* rp = M3[q];
        float s = b4[jf];
        #pragma unroll
        for (int k = 0; k < 64; k++) s = fmaf(rp[k], W4[k * 10 + jf], s);
        out[(r0 + q) * 10 + jf] = s;
    }
}

extern "C" void kernel_launch(void* const* d_in, const int* in_sizes, int n_in,
                              void* d_out, int out_size, void* d_ws, size_t ws_size,
                              hipStream_t stream) {
    const float* x     = (const float*)d_in[0];
    const int*   ei    = (const int*) d_in[1];
    const int*   batch = (const int*) d_in[2];
    const float *W1l = (const float*)d_in[3],  *b1l = (const float*)d_in[4],  *W1r = (const float*)d_in[5];
    const float *W2l = (const float*)d_in[6],  *b2l = (const float*)d_in[7],  *W2r = (const float*)d_in[8];
    const float *W3l = (const float*)d_in[9],  *b3l = (const float*)d_in[10], *W3r = (const float*)d_in[11];
    const float *lin1_w = (const float*)d_in[12], *lin1_b = (const float*)d_in[13];
    const float *g1 = (const float*)d_in[14], *be1 = (const float*)d_in[15];
    const float *lin2_w = (const float*)d_in[16], *lin2_b = (const float*)d_in[17];
    const float *g2 = (const float*)d_in[18], *be2 = (const float*)d_in[19];
    const float *lin3_w = (const float*)d_in[20], *lin3_b = (const float*)d_in[21];
    const float *g3 = (const float*)d_in[22], *be3 = (const float*)d_in[23];
    const float *lin4_w = (const float*)d_in[24], *lin4_b = (const float*)d_in[25];

    const int* srcp = ei;
    const int* dstp = ei + N_EDGES;

    // ---- workspace layout ----
    const long NF = (long)N_NODES * HD;              // 3,200,000
    char* wsb  = (char*)d_ws;
    int*  cnti = (int*)wsb;                          // 50,048
    int*  bar  = cnti + 50048;                       // 8
    float* gstat = (float*)(bar + 8);                // 896 (zeroed with cnti)
    int*  pos  = (int*)(gstat + 896);                // 800,000
    int*  off  = pos  + 800000;                      // 50,056
    int*  nbr  = off  + 50056;                       // 800,000
    int*  bsum = nbr  + 800000;                      // 256
    int*  gb   = bsum + 256;                         // 264 (257 used)
    float* invc = (float*)(gb + 264);                // 256
    int2* bounds = (int2*)(invc + 256);              // 50,000 int2 (8B-aligned)
    bf16* B    = (bf16*)(bounds + 50000);            // 3,200,000 bf16
    float* H1  = (float*)(B + NF);                   // 3,200,000
    float* H2  = H1  + NF;                           // 3,200,000
    float* cb  = H2  + NF;                           // 16,384
    float* endp= cb  + NUM_GRAPHS * HD;

    const size_t NEED = (size_t)((char*)endp - wsb);
    if (ws_size < NEED) {
        k_diag<<<(out_size + 255) / 256, 256, 0, stream>>>((float*)d_out, out_size,
                                                           (float)(ws_size >> 20));
        return;
    }

    const int TB = 256;
    const int gNF = (int)((NF + TB - 1) / TB);        // 12500 (= exactly 50000 nodes)
    const int gX16 = (N_NODES + 15) / 16;             // 3125 (all xforms; = edges/256)

    hipMemsetAsync(cnti, 0, (50048 + 8 + 896) * sizeof(int), stream);

    // ---- xform1 + CSR count (merged: identical 3125x256 grids) ----
    k_xform3<IN_DIM, 16, true><<<gX16, TB, 0, stream>>>(
        x, W1l, W1r, b1l, B, H1, dstp, batch, cnti, pos, gb);
    k_scan1<<<SCAN_NB, TB, 0, stream>>>(cnti, off, bsum);
    k_scan3<<<SCAN_NB, TB, 0, stream>>>(off, bsum, cnti, gb, invc, bounds, cb);
    k_fill<<<gX16, TB, 0, stream>>>(srcp, dstp, off, pos, nbr);

    // ---- SAGE layers (bf16 messages, quad-row gather) ----
    k_gather<false><<<gNF, TB, 0, stream>>>(bounds, nbr, B, H1, batch, invc, cb);
    k_xform3<HD, 16, false><<<gX16, TB, 0, stream>>>(
        H1, W2l, W2r, b2l, B, H2, nullptr, nullptr, nullptr, nullptr, nullptr);
    k_gather<false><<<gNF, TB, 0, stream>>>(bounds, nbr, B, H2, batch, invc, cb);
    k_xform3<HD, 16, false><<<gX16, TB, 0, stream>>>(
        H2, W3l, W3r, b3l, B, H1, nullptr, nullptr, nullptr, nullptr, nullptr);
    // last gather: fused global-mean-pool into cb (H1 never written back)
    k_gather<true><<<gNF, TB, 0, stream>>>(bounds, nbr, B, H1, batch, invc, cb);

    // ---- fused head: row-partitioned, LDS-staged weights ----
    k_head<<<NB_HEAD, TB, 0, stream>>>(bar, gstat,
                                       lin1_w, lin1_b, g1, be1,
                                       lin2_w, lin2_b, g2, be2,
                                       lin3_w, lin3_b, g3, be3,
                                       lin4_w, lin4_b,
                                       cb, (float*)d_out);
}